// Round 2
// baseline (158.379 us; speedup 1.0000x reference)
//
#include <hip/hip_runtime.h>
#include <hip/hip_bf16.h>

#define BB 8
#define NN 512
#define DD 256
#define NROWS (BB*NN)   // 4096

// out[row,d] = sum_k x[row,k] * W[d,k] + bias[d]
// x is either gathered f32 rows (emb[idx[row]]) or a dense f32 array.
// 16 rows/block, 256 threads; thread t -> dims d0=(t&127)*2, rows half=(t>>7)*8..+8
__global__ __launch_bounds__(256) void row_linear(
    const float* __restrict__ W, const float* __restrict__ bias,
    const float* __restrict__ emb, const int* __restrict__ idx,
    const float* __restrict__ xin, float* __restrict__ out)
{
    __shared__ __align__(16) float xt[16][DD];
    const int t = threadIdx.x;
    const int r0 = blockIdx.x * 16;
    for (int rr = 0; rr < 16; ++rr) {
        int row = r0 + rr;
        if (idx) {
            int nid = idx[row];
            xt[rr][t] = emb[(size_t)nid*DD + t];
        } else {
            xt[rr][t] = xin[(size_t)row*DD + t];
        }
    }
    __syncthreads();

    const int d0 = (t & 127) * 2;
    const int half = t >> 7;           // 0 or 1 -> rows [half*8, half*8+8)
    float acc[8][2];
    #pragma unroll
    for (int r = 0; r < 8; ++r) { acc[r][0] = 0.f; acc[r][1] = 0.f; }

    const float4* W0 = (const float4*)(W + (size_t)d0*DD);
    const float4* W1 = (const float4*)(W + (size_t)(d0+1)*DD);
    for (int k8 = 0; k8 < DD/8; ++k8) {
        float4 w0a = W0[2*k8], w0b = W0[2*k8+1];
        float4 w1a = W1[2*k8], w1b = W1[2*k8+1];
        #pragma unroll
        for (int r = 0; r < 8; ++r) {
            const float4* x4 = (const float4*)&xt[half*8 + r][k8*8];
            float4 xa = x4[0], xb = x4[1];
            acc[r][0] += w0a.x*xa.x + w0a.y*xa.y + w0a.z*xa.z + w0a.w*xa.w
                       + w0b.x*xb.x + w0b.y*xb.y + w0b.z*xb.z + w0b.w*xb.w;
            acc[r][1] += w1a.x*xa.x + w1a.y*xa.y + w1a.z*xa.z + w1a.w*xa.w
                       + w1b.x*xb.x + w1b.y*xb.y + w1b.z*xb.z + w1b.w*xb.w;
        }
    }
    float b0 = bias[d0];
    float b1 = bias[d0+1];
    #pragma unroll
    for (int r = 0; r < 8; ++r) {
        int row = r0 + half*8 + r;
        float2 v; v.x = acc[r][0] + b0; v.y = acc[r][1] + b1;
        *(float2*)&out[(size_t)row*DD + d0] = v;
    }
}

// a[row] = h[row,:]·w[0:256]   + f[row,:]·w[512:544]
// c[row] = h[row,:]·w[256:512] + f[row,:]·w[544:576]
__global__ __launch_bounds__(256) void row_scalars(
    const float* __restrict__ h, const int* __restrict__ flagidx,
    const float* __restrict__ flag_emb, const float* __restrict__ w,
    float* __restrict__ a, float* __restrict__ c)
{
    const int wave = threadIdx.x >> 6, lane = threadIdx.x & 63;
    const int row = blockIdx.x*4 + wave;
    const float* hr = h + (size_t)row*DD;
    float pa = 0.f, pc = 0.f;
    #pragma unroll
    for (int s = 0; s < 4; ++s) {
        int k = lane + s*64;
        float hv = hr[k];
        pa += hv * w[k];
        pc += hv * w[256+k];
    }
    if (lane < 32) {
        int fi = flagidx[row];
        float fv = flag_emb[fi*32 + lane];
        pa += fv * w[512+lane];
        pc += fv * w[544+lane];
    }
    #pragma unroll
    for (int off = 32; off > 0; off >>= 1) {
        pa += __shfl_down(pa, off);
        pc += __shfl_down(pc, off);
    }
    if (lane == 0) { a[row] = pa; c[row] = pc; }
}

// One block per (b, 8-column tile). Computes logits, softmax over i, then
// out[j,d] = (1/den_j) * sum_i exp(l[i,j]-m_j) * h[b,i,d].
__global__ __launch_bounds__(256) void gat_attn(
    const int* __restrict__ adj, const int* __restrict__ etype,
    const float* __restrict__ edge_emb, const float* __restrict__ w,
    const float* __restrict__ bptr,
    const float* __restrict__ a, const float* __restrict__ c,
    const float* __restrict__ h,
    float* __restrict__ out, int apply_sigmoid)
{
    __shared__ __align__(16) float p[NN*8];   // [i][j], 16 KB
    __shared__ float edot[16];
    __shared__ float cj[8];
    __shared__ float red[32*8];
    __shared__ float mj[8];
    __shared__ float invden[8];

    const int t = threadIdx.x;
    const int b = blockIdx.x >> 6;
    const int j0 = (blockIdx.x & 63) << 3;

    if (t < 16) {
        float s = 0.f;
        for (int e2 = 0; e2 < 32; ++e2)
            s += edge_emb[t*32 + e2] * w[576 + e2];
        edot[t] = s;
    } else if (t < 24) {
        cj[t-16] = c[b*NN + j0 + (t-16)];
    }
    const float bias = bptr[0];
    __syncthreads();

    // logits
    const int base = b*NN*NN;
    #pragma unroll
    for (int it = 0; it < NN*8/256; ++it) {
        int idx = it*256 + t;            // == i*8 + j
        int i = idx >> 3, j = idx & 7;
        int g = base + i*NN + j0 + j;
        int ad = adj[g];
        int et = etype[g];
        float l = a[b*NN + i] + cj[j] + edot[et] + bias;
        l = (l > 0.f) ? l : 0.1f*l;
        p[idx] = ad ? l : -1.0e30f;
    }
    __syncthreads();

    // per-column (j) max over i
    const int j = t & 7, grp = t >> 3;   // grp 0..31
    float m = -3.0e38f;
    #pragma unroll
    for (int s = 0; s < 16; ++s) m = fmaxf(m, p[(grp + s*32)*8 + j]);
    red[grp*8 + j] = m;
    __syncthreads();
    if (t < 8) {
        float mm = red[t];
        for (int g2 = 1; g2 < 32; ++g2) mm = fmaxf(mm, red[g2*8 + t]);
        mj[t] = mm;
    }
    __syncthreads();
    const float mmax = mj[j];
    float ssum = 0.f;
    #pragma unroll
    for (int s = 0; s < 16; ++s) {
        int ix = (grp + s*32)*8 + j;
        float v = __expf(p[ix] - mmax);
        p[ix] = v;
        ssum += v;
    }
    red[grp*8 + j] = ssum;
    __syncthreads();
    if (t < 8) {
        float sm = 0.f;
        for (int g2 = 0; g2 < 32; ++g2) sm += red[g2*8 + t];
        invden[t] = 1.f / sm;
    }
    __syncthreads();

    // aggregation: thread t handles dim d = t for all 8 columns
    float acc[8];
    #pragma unroll
    for (int q = 0; q < 8; ++q) acc[q] = 0.f;
    const float* hb = h + (size_t)(b*NN)*DD + t;
    const float4* pv = (const float4*)p;
    #pragma unroll 4
    for (int i = 0; i < NN; ++i) {
        float hv = hb[(size_t)i*DD];
        float4 p0 = pv[i*2], p1 = pv[i*2+1];
        acc[0] += p0.x*hv; acc[1] += p0.y*hv; acc[2] += p0.z*hv; acc[3] += p0.w*hv;
        acc[4] += p1.x*hv; acc[5] += p1.y*hv; acc[6] += p1.z*hv; acc[7] += p1.w*hv;
    }
    #pragma unroll
    for (int q = 0; q < 8; ++q) {
        float v = acc[q] * invden[q];
        size_t o = (size_t)(b*NN + j0 + q)*DD + t;
        out[o] = apply_sigmoid ? (1.f/(1.f + __expf(-v))) : v;
    }
}

extern "C" void kernel_launch(void* const* d_in, const int* in_sizes, int n_in,
                              void* d_out, int out_size, void* d_ws, size_t ws_size,
                              hipStream_t stream) {
    (void)in_sizes; (void)n_in; (void)out_size; (void)ws_size;
    const int*   adj       = (const int*)d_in[0];
    const int*   head_nodes= (const int*)d_in[1];
    const int*   head_flag = (const int*)d_in[2];
    const int*   etype     = (const int*)d_in[3];
    const float* node_emb  = (const float*)d_in[4];
    const float* edge_emb  = (const float*)d_in[5];
    const float* flag_emb  = (const float*)d_in[6];
    const float* t1_w      = (const float*)d_in[7];
    const float* t1_b      = (const float*)d_in[8];
    const float* w1        = (const float*)d_in[9];
    const float* b1        = (const float*)d_in[10];
    const float* t2_w      = (const float*)d_in[11];
    const float* t2_b      = (const float*)d_in[12];
    const float* w2        = (const float*)d_in[13];
    const float* b2        = (const float*)d_in[14];

    float* h  = (float*)d_ws;                      // 4096*256 (reused for h2)
    float* tt = h  + (size_t)NROWS*DD;             // 4096*256 (sigmoid(out1))
    float* a1 = tt + (size_t)NROWS*DD;
    float* c1 = a1 + NROWS;
    float* a2 = c1 + NROWS;
    float* c2 = a2 + NROWS;

    row_linear<<<NROWS/16, 256, 0, stream>>>(t1_w, t1_b, node_emb, head_nodes, nullptr, h);
    row_scalars<<<NROWS/4, 256, 0, stream>>>(h, head_flag, flag_emb, w1, a1, c1);
    gat_attn<<<BB*(NN/8), 256, 0, stream>>>(adj, etype, edge_emb, w1, b1, a1, c1, h,
                                            tt, 1);
    // h2 overwrites h (h no longer needed after gat_attn layer 1)
    row_linear<<<NROWS/16, 256, 0, stream>>>(t2_w, t2_b, nullptr, nullptr, tt, h);
    row_scalars<<<NROWS/4, 256, 0, stream>>>(h, head_flag, flag_emb, w2, a2, c2);
    gat_attn<<<BB*(NN/8), 256, 0, stream>>>(adj, etype, edge_emb, w2, b2, a2, c2, h,
                                            (float*)d_out, 0);
}

// Round 3
// 118.612 us; speedup vs baseline: 1.3353x; 1.3353x over previous
//
#include <hip/hip_runtime.h>
#include <hip/hip_bf16.h>

#define BB 8
#define NN 512
#define DD 256
#define NROWS (BB*NN)   // 4096
#define JT 16           // attn j-tile

using bf16x8 = __attribute__((ext_vector_type(8))) short;
using f32x4  = __attribute__((ext_vector_type(4))) float;

__device__ __forceinline__ unsigned short f2bf(float x) {
    union { float f; unsigned int u; } v; v.f = x;
    unsigned int r = (v.u + 0x7fffu + ((v.u >> 16) & 1u)) >> 16;
    return (unsigned short)r;
}

// out[row,d] = sum_k x[row,k] * W[d,k] + bias[d]; also writes hT[b][d][i] bf16.
// 8 rows/block, 512 blocks. thread t -> dims d0=(t&127)*2, rows half=(t>>7)*4..+4
__global__ __launch_bounds__(256) void row_linear(
    const float* __restrict__ W, const float* __restrict__ bias,
    const float* __restrict__ emb, const int* __restrict__ idx,
    const float* __restrict__ xin, float* __restrict__ out,
    unsigned short* __restrict__ hT)
{
    __shared__ __align__(16) float xt[8][DD];
    const int t = threadIdx.x;
    const int r0 = blockIdx.x * 8;
    for (int rr = 0; rr < 8; ++rr) {
        int row = r0 + rr;
        if (idx) xt[rr][t] = emb[(size_t)idx[row]*DD + t];
        else     xt[rr][t] = xin[(size_t)row*DD + t];
    }
    __syncthreads();

    const int d0 = (t & 127) * 2;
    const int half = t >> 7;           // rows [half*4, half*4+4)
    float acc[4][2];
    #pragma unroll
    for (int r = 0; r < 4; ++r) { acc[r][0] = 0.f; acc[r][1] = 0.f; }

    const float4* W0 = (const float4*)(W + (size_t)d0*DD);
    const float4* W1 = (const float4*)(W + (size_t)(d0+1)*DD);
    for (int k8 = 0; k8 < DD/8; ++k8) {
        float4 w0a = W0[2*k8], w0b = W0[2*k8+1];
        float4 w1a = W1[2*k8], w1b = W1[2*k8+1];
        #pragma unroll
        for (int r = 0; r < 4; ++r) {
            const float4* x4 = (const float4*)&xt[half*4 + r][k8*8];
            float4 xa = x4[0], xb = x4[1];
            acc[r][0] += w0a.x*xa.x + w0a.y*xa.y + w0a.z*xa.z + w0a.w*xa.w
                       + w0b.x*xb.x + w0b.y*xb.y + w0b.z*xb.z + w0b.w*xb.w;
            acc[r][1] += w1a.x*xa.x + w1a.y*xa.y + w1a.z*xa.z + w1a.w*xa.w
                       + w1b.x*xb.x + w1b.y*xb.y + w1b.z*xb.z + w1b.w*xb.w;
        }
    }
    float b0 = bias[d0], b1 = bias[d0+1];
    #pragma unroll
    for (int r = 0; r < 4; ++r) {
        int row = r0 + half*4 + r;
        float2 v; v.x = acc[r][0] + b0; v.y = acc[r][1] + b1;
        *(float2*)&out[(size_t)row*DD + d0] = v;
    }
    // transposed bf16 write: hT[b][d][i], 4 consecutive i per thread per d
    const int b  = r0 >> 9;
    const int il = (r0 & 511) + half*4;
    {
        ushort4 u;
        u.x = f2bf(acc[0][0] + b0); u.y = f2bf(acc[1][0] + b0);
        u.z = f2bf(acc[2][0] + b0); u.w = f2bf(acc[3][0] + b0);
        *(ushort4*)&hT[(size_t)b*DD*NN + (size_t)d0*NN + il] = u;
        u.x = f2bf(acc[0][1] + b1); u.y = f2bf(acc[1][1] + b1);
        u.z = f2bf(acc[2][1] + b1); u.w = f2bf(acc[3][1] + b1);
        *(ushort4*)&hT[(size_t)b*DD*NN + (size_t)(d0+1)*NN + il] = u;
    }
}

// a[row] = h[row,:]·w[0:256]   + f[row,:]·w[512:544]
// c[row] = h[row,:]·w[256:512] + f[row,:]·w[544:576]
__global__ __launch_bounds__(256) void row_scalars(
    const float* __restrict__ h, const int* __restrict__ flagidx,
    const float* __restrict__ flag_emb, const float* __restrict__ w,
    float* __restrict__ a, float* __restrict__ c)
{
    const int wave = threadIdx.x >> 6, lane = threadIdx.x & 63;
    const int row = blockIdx.x*4 + wave;
    const float* hr = h + (size_t)row*DD;
    float pa = 0.f, pc = 0.f;
    #pragma unroll
    for (int s = 0; s < 4; ++s) {
        int k = lane + s*64;
        float hv = hr[k];
        pa += hv * w[k];
        pc += hv * w[256+k];
    }
    if (lane < 32) {
        int fi = flagidx[row];
        float fv = flag_emb[fi*32 + lane];
        pa += fv * w[512+lane];
        pc += fv * w[544+lane];
    }
    #pragma unroll
    for (int off = 32; off > 0; off >>= 1) {
        pa += __shfl_down(pa, off);
        pc += __shfl_down(pc, off);
    }
    if (lane == 0) { a[row] = pa; c[row] = pc; }
}

// One block per (b, 16-column tile). logits -> softmax over i -> bf16 P in LDS
// -> MFMA aggregation out[j,d] = sum_i P[i,j] h[i,d] using hT[b][d][i].
__global__ __launch_bounds__(256) void attn_fused(
    const int* __restrict__ adj, const int* __restrict__ etype,
    const float* __restrict__ edge_emb, const float* __restrict__ w,
    const float* __restrict__ bptr,
    const float* __restrict__ a, const float* __restrict__ c,
    const unsigned short* __restrict__ hT,
    float* __restrict__ out, int apply_sigmoid)
{
    __shared__ __align__(16) float p[NN][JT+1];              // 34.8 KB
    __shared__ __align__(16) unsigned short Pb[JT][NN+8];    // 16.6 KB
    __shared__ float edot[16];
    __shared__ float cjs[JT];
    __shared__ float red[16][JT];
    __shared__ float mj[JT];
    __shared__ float invden[JT];

    const int t = threadIdx.x;
    const int b  = blockIdx.x >> 5;
    const int j0 = (blockIdx.x & 31) * JT;

    if (t < 16) {
        float s = 0.f;
        for (int e2 = 0; e2 < 32; ++e2)
            s += edge_emb[t*32 + e2] * w[576 + e2];
        edot[t] = s;
    } else if (t < 32) {
        cjs[t-16] = c[b*NN + j0 + (t-16)];
    }
    const float bias = bptr[0];
    __syncthreads();

    // ---- logits ----
    const int base = b*NN*NN;
    #pragma unroll 4
    for (int it = 0; it < NN*JT/256; ++it) {
        int idx = it*256 + t;            // == i*16 + j
        int i = idx >> 4, j = idx & 15;
        int g = base + i*NN + j0 + j;
        int ad = adj[g];
        int et = etype[g];
        float l = a[b*NN + i] + cjs[j] + edot[et] + bias;
        l = (l > 0.f) ? l : 0.1f*l;
        p[i][j] = ad ? l : -1.0e30f;
    }
    __syncthreads();

    // ---- softmax over i (per column j) ----
    const int j = t & 15, grp = t >> 4;   // grp 0..15, each handles 32 i's
    float m = -3.0e38f;
    #pragma unroll
    for (int s = 0; s < 32; ++s) m = fmaxf(m, p[grp + s*16][j]);
    red[grp][j] = m;
    __syncthreads();
    if (t < 16) {
        float mm = red[0][t];
        for (int g2 = 1; g2 < 16; ++g2) mm = fmaxf(mm, red[g2][t]);
        mj[t] = mm;
    }
    __syncthreads();
    const float mmax = mj[j];
    float ssum = 0.f;
    #pragma unroll
    for (int s = 0; s < 32; ++s) {
        float v = __expf(p[grp + s*16][j] - mmax);
        p[grp + s*16][j] = v;
        ssum += v;
    }
    red[grp][j] = ssum;
    __syncthreads();
    if (t < 16) {
        float sm = 0.f;
        for (int g2 = 0; g2 < 16; ++g2) sm += red[g2][t];
        invden[t] = 1.f / sm;
    }
    __syncthreads();

    // ---- normalize + pack transposed bf16: Pb[j][i] ----
    const float inv = invden[j];
    #pragma unroll
    for (int s = 0; s < 16; ++s) {
        int i = grp*2 + s*32;
        ushort2 u;
        u.x = f2bf(p[i  ][j] * inv);
        u.y = f2bf(p[i+1][j] * inv);
        *(ushort2*)&Pb[j][i] = u;
    }
    __syncthreads();

    // ---- MFMA: out[16 j][256 d] = P^T (16x512) x h (512x256) ----
    const int wave = t >> 6, lane = t & 63;
    const int dw = wave * 64;
    const int lrow = lane & 15;          // j (A row / D col-group)
    const int kg   = lane >> 4;          // k-group
    f32x4 acc[4];
    #pragma unroll
    for (int n = 0; n < 4; ++n) acc[n] = (f32x4){0.f,0.f,0.f,0.f};

    const unsigned short* hTb = hT + (size_t)b*DD*NN;
    const unsigned short* hp[4];
    #pragma unroll
    for (int n = 0; n < 4; ++n)
        hp[n] = hTb + (size_t)(dw + n*16 + lrow)*NN + kg*8;

    #pragma unroll 2
    for (int ks = 0; ks < NN/32; ++ks) {
        int k0 = ks*32;
        bf16x8 afr = *(const bf16x8*)&Pb[lrow][kg*8 + k0];
        #pragma unroll
        for (int n = 0; n < 4; ++n) {
            bf16x8 bfr = *(const bf16x8*)(hp[n] + k0);
            acc[n] = __builtin_amdgcn_mfma_f32_16x16x32_bf16(afr, bfr, acc[n], 0, 0, 0);
        }
    }

    // ---- epilogue: C/D layout col=lane&15 (d), row=(lane>>4)*4+reg (j) ----
    #pragma unroll
    for (int n = 0; n < 4; ++n) {
        #pragma unroll
        for (int r = 0; r < 4; ++r) {
            float v = acc[n][r];
            if (apply_sigmoid) v = 1.f/(1.f + __expf(-v));
            int jj = j0 + kg*4 + r;
            int dd = dw + n*16 + lrow;
            out[(size_t)(b*NN + jj)*DD + dd] = v;
        }
    }
}

extern "C" void kernel_launch(void* const* d_in, const int* in_sizes, int n_in,
                              void* d_out, int out_size, void* d_ws, size_t ws_size,
                              hipStream_t stream) {
    (void)in_sizes; (void)n_in; (void)out_size; (void)ws_size;
    const int*   adj       = (const int*)d_in[0];
    const int*   head_nodes= (const int*)d_in[1];
    const int*   head_flag = (const int*)d_in[2];
    const int*   etype     = (const int*)d_in[3];
    const float* node_emb  = (const float*)d_in[4];
    const float* edge_emb  = (const float*)d_in[5];
    const float* flag_emb  = (const float*)d_in[6];
    const float* t1_w      = (const float*)d_in[7];
    const float* t1_b      = (const float*)d_in[8];
    const float* w1        = (const float*)d_in[9];
    const float* b1        = (const float*)d_in[10];
    const float* t2_w      = (const float*)d_in[11];
    const float* t2_b      = (const float*)d_in[12];
    const float* w2        = (const float*)d_in[13];
    const float* b2        = (const float*)d_in[14];

    float* h  = (float*)d_ws;                        // 4 MB (reused for h2)
    float* tt = h  + (size_t)NROWS*DD;               // 4 MB sigmoid(out1)
    unsigned short* hT = (unsigned short*)(tt + (size_t)NROWS*DD); // 2 MB bf16
    float* a1 = (float*)(hT + (size_t)NROWS*DD);
    float* c1 = a1 + NROWS;
    float* a2 = c1 + NROWS;
    float* c2 = a2 + NROWS;

    row_linear<<<NROWS/8, 256, 0, stream>>>(t1_w, t1_b, node_emb, head_nodes,
                                            nullptr, h, hT);
    row_scalars<<<NROWS/4, 256, 0, stream>>>(h, head_flag, flag_emb, w1, a1, c1);
    attn_fused<<<BB*(NN/JT), 256, 0, stream>>>(adj, etype, edge_emb, w1, b1,
                                               a1, c1, hT, tt, 1);
    row_linear<<<NROWS/8, 256, 0, stream>>>(t2_w, t2_b, nullptr, nullptr, tt, h, hT);
    row_scalars<<<NROWS/4, 256, 0, stream>>>(h, head_flag, flag_emb, w2, a2, c2);
    attn_fused<<<BB*(NN/JT), 256, 0, stream>>>(adj, etype, edge_emb, w2, b2,
                                               a2, c2, hT, (float*)d_out, 0);
}

// Round 4
// 79.262 us; speedup vs baseline: 1.9982x; 1.4964x over previous
//
#include <hip/hip_runtime.h>
#include <hip/hip_bf16.h>

#define BB 8
#define NN 512
#define DD 256
#define NROWS (BB*NN)   // 4096
#define JT 16           // attn j-tile

using bf16x8 = __attribute__((ext_vector_type(8))) short;
using f32x4  = __attribute__((ext_vector_type(4))) float;

__device__ __forceinline__ unsigned short f2bf(float x) {
    union { float f; unsigned int u; } v; v.f = x;
    unsigned int r = (v.u + 0x7fffu + ((v.u >> 16) & 1u)) >> 16;
    return (unsigned short)r;
}

// Convert both weight matrices f32 [256][256] -> bf16 [d][k]
__global__ __launch_bounds__(256) void conv_w(
    const float* __restrict__ w1, const float* __restrict__ w2,
    unsigned short* __restrict__ o1, unsigned short* __restrict__ o2)
{
    int i = blockIdx.x * 256 + threadIdx.x;   // 0..65535
    o1[i] = f2bf(w1[i]);
    o2[i] = f2bf(w2[i]);
}

// MFMA linear: out[row,d] = sum_k X[src(row),k] * W[d,k] + bias[d]
// Block: 16 rows x 256 d, 4 waves (wave w -> d in [w*64, w*64+64)).
// Also writes hT[b][d][i] bf16 for the attn MFMA B-operand.
__global__ __launch_bounds__(256) void lin_mfma(
    const unsigned short* __restrict__ Wbf, const float* __restrict__ bias,
    const float* __restrict__ X, const int* __restrict__ idx,
    float* __restrict__ out, unsigned short* __restrict__ hT)
{
    const int t = threadIdx.x;
    const int wave = t >> 6, lane = t & 63;
    const int lrow = lane & 15, kg = lane >> 4;
    const int r0 = blockIdx.x * 16;
    const int dw = wave * 64;

    const int arow = r0 + lrow;
    const int nid = idx ? idx[arow] : arow;
    const float4* xr = (const float4*)(X + (size_t)nid * DD);

    f32x4 acc[4];
    #pragma unroll
    for (int n = 0; n < 4; ++n) acc[n] = (f32x4){0.f, 0.f, 0.f, 0.f};

    #pragma unroll
    for (int ks = 0; ks < DD/32; ++ks) {
        float4 xa = xr[ks*8 + kg*2];
        float4 xb = xr[ks*8 + kg*2 + 1];
        bf16x8 af;
        af[0] = (short)f2bf(xa.x); af[1] = (short)f2bf(xa.y);
        af[2] = (short)f2bf(xa.z); af[3] = (short)f2bf(xa.w);
        af[4] = (short)f2bf(xb.x); af[5] = (short)f2bf(xb.y);
        af[6] = (short)f2bf(xb.z); af[7] = (short)f2bf(xb.w);
        #pragma unroll
        for (int n = 0; n < 4; ++n) {
            bf16x8 bf = *(const bf16x8*)(Wbf + (size_t)(dw + n*16 + lrow)*DD
                                          + ks*32 + kg*8);
            acc[n] = __builtin_amdgcn_mfma_f32_16x16x32_bf16(af, bf, acc[n], 0, 0, 0);
        }
    }

    // epilogue: D row (m) = kg*4+r, D col (d) = dw + n*16 + lrow
    const int b  = r0 >> 9;
    const int i0 = (r0 & 511) + kg*4;
    #pragma unroll
    for (int n = 0; n < 4; ++n) {
        int d = dw + n*16 + lrow;
        float bv = bias[d];
        ushort4 u;
        #pragma unroll
        for (int r = 0; r < 4; ++r) {
            float v = acc[n][r] + bv;
            out[(size_t)(r0 + kg*4 + r)*DD + d] = v;
            ((unsigned short*)&u)[r] = f2bf(v);
        }
        *(ushort4*)&hT[(size_t)b*DD*NN + (size_t)d*NN + i0] = u;
    }
}

// a[row] = h[row,:]·w[0:256]   + f[row,:]·w[512:544]
// c[row] = h[row,:]·w[256:512] + f[row,:]·w[544:576]
__global__ __launch_bounds__(256) void row_scalars(
    const float* __restrict__ h, const int* __restrict__ flagidx,
    const float* __restrict__ flag_emb, const float* __restrict__ w,
    float* __restrict__ a, float* __restrict__ c)
{
    const int wave = threadIdx.x >> 6, lane = threadIdx.x & 63;
    const int row = blockIdx.x*4 + wave;
    const float* hr = h + (size_t)row*DD;
    float pa = 0.f, pc = 0.f;
    #pragma unroll
    for (int s = 0; s < 4; ++s) {
        int k = lane + s*64;
        float hv = hr[k];
        pa += hv * w[k];
        pc += hv * w[256+k];
    }
    if (lane < 32) {
        int fi = flagidx[row];
        float fv = flag_emb[fi*32 + lane];
        pa += fv * w[512+lane];
        pc += fv * w[544+lane];
    }
    #pragma unroll
    for (int off = 32; off > 0; off >>= 1) {
        pa += __shfl_down(pa, off);
        pc += __shfl_down(pc, off);
    }
    if (lane == 0) { a[row] = pa; c[row] = pc; }
}

// One block per (b, 16-column tile). logits -> softmax over i -> bf16 P in LDS
// -> MFMA aggregation out[j,d] = sum_i P[i,j] h[i,d] using hT[b][d][i].
__global__ __launch_bounds__(256) void attn_fused(
    const int* __restrict__ adj, const int* __restrict__ etype,
    const float* __restrict__ edge_emb, const float* __restrict__ w,
    const float* __restrict__ bptr,
    const float* __restrict__ a, const float* __restrict__ c,
    const unsigned short* __restrict__ hT,
    float* __restrict__ out, int apply_sigmoid)
{
    __shared__ __align__(16) float p[NN][JT+1];              // 34.8 KB
    __shared__ __align__(16) unsigned short Pb[JT][NN+8];    // 16.6 KB
    __shared__ float edot[16];
    __shared__ float cjs[JT];
    __shared__ float red[16][JT];
    __shared__ float mj[JT];
    __shared__ float invden[JT];

    const int t = threadIdx.x;
    const int b  = blockIdx.x >> 5;
    const int j0 = (blockIdx.x & 31) * JT;

    if (t < 16) {
        float s = 0.f;
        for (int e2 = 0; e2 < 32; ++e2)
            s += edge_emb[t*32 + e2] * w[576 + e2];
        edot[t] = s;
    } else if (t < 32) {
        cjs[t-16] = c[b*NN + j0 + (t-16)];
    }
    const float bias = bptr[0];
    __syncthreads();

    // ---- logits ----
    const int base = b*NN*NN;
    #pragma unroll 4
    for (int it = 0; it < NN*JT/256; ++it) {
        int idx = it*256 + t;            // == i*16 + j
        int i = idx >> 4, j = idx & 15;
        int g = base + i*NN + j0 + j;
        int ad = adj[g];
        int et = etype[g];
        float l = a[b*NN + i] + cjs[j] + edot[et] + bias;
        l = (l > 0.f) ? l : 0.1f*l;
        p[i][j] = ad ? l : -1.0e30f;
    }
    __syncthreads();

    // ---- softmax over i (per column j) ----
    const int j = t & 15, grp = t >> 4;   // grp 0..15, each handles 32 i's
    float m = -3.0e38f;
    #pragma unroll
    for (int s = 0; s < 32; ++s) m = fmaxf(m, p[grp + s*16][j]);
    red[grp][j] = m;
    __syncthreads();
    if (t < 16) {
        float mm = red[0][t];
        for (int g2 = 1; g2 < 16; ++g2) mm = fmaxf(mm, red[g2][t]);
        mj[t] = mm;
    }
    __syncthreads();
    const float mmax = mj[j];
    float ssum = 0.f;
    #pragma unroll
    for (int s = 0; s < 32; ++s) {
        float v = __expf(p[grp + s*16][j] - mmax);
        p[grp + s*16][j] = v;
        ssum += v;
    }
    red[grp][j] = ssum;
    __syncthreads();
    if (t < 16) {
        float sm = 0.f;
        for (int g2 = 0; g2 < 16; ++g2) sm += red[g2][t];
        invden[t] = 1.f / sm;
    }
    __syncthreads();

    // ---- normalize + pack transposed bf16: Pb[j][i] ----
    const float inv = invden[j];
    #pragma unroll
    for (int s = 0; s < 16; ++s) {
        int i = grp*2 + s*32;
        ushort2 u;
        u.x = f2bf(p[i  ][j] * inv);
        u.y = f2bf(p[i+1][j] * inv);
        *(ushort2*)&Pb[j][i] = u;
    }
    __syncthreads();

    // ---- MFMA: out[16 j][256 d] = P^T (16x512) x h (512x256) ----
    const int wave = t >> 6, lane = t & 63;
    const int dw = wave * 64;
    const int lrow = lane & 15;          // A row (j) / B col (d)
    const int kg   = lane >> 4;          // k-group
    f32x4 acc[4];
    #pragma unroll
    for (int n = 0; n < 4; ++n) acc[n] = (f32x4){0.f,0.f,0.f,0.f};

    const unsigned short* hTb = hT + (size_t)b*DD*NN;
    const unsigned short* hp[4];
    #pragma unroll
    for (int n = 0; n < 4; ++n)
        hp[n] = hTb + (size_t)(dw + n*16 + lrow)*NN + kg*8;

    #pragma unroll 2
    for (int ks = 0; ks < NN/32; ++ks) {
        int k0 = ks*32;
        bf16x8 afr = *(const bf16x8*)&Pb[lrow][kg*8 + k0];
        #pragma unroll
        for (int n = 0; n < 4; ++n) {
            bf16x8 bfr = *(const bf16x8*)(hp[n] + k0);
            acc[n] = __builtin_amdgcn_mfma_f32_16x16x32_bf16(afr, bfr, acc[n], 0, 0, 0);
        }
    }

    // ---- epilogue: C/D layout col=lane&15 (d), row=(lane>>4)*4+reg (j) ----
    #pragma unroll
    for (int n = 0; n < 4; ++n) {
        #pragma unroll
        for (int r = 0; r < 4; ++r) {
            float v = acc[n][r];
            if (apply_sigmoid) v = 1.f/(1.f + __expf(-v));
            int jj = j0 + kg*4 + r;
            int dd = dw + n*16 + lrow;
            out[(size_t)(b*NN + jj)*DD + dd] = v;
        }
    }
}

extern "C" void kernel_launch(void* const* d_in, const int* in_sizes, int n_in,
                              void* d_out, int out_size, void* d_ws, size_t ws_size,
                              hipStream_t stream) {
    (void)in_sizes; (void)n_in; (void)out_size; (void)ws_size;
    const int*   adj       = (const int*)d_in[0];
    const int*   head_nodes= (const int*)d_in[1];
    const int*   head_flag = (const int*)d_in[2];
    const int*   etype     = (const int*)d_in[3];
    const float* node_emb  = (const float*)d_in[4];
    const float* edge_emb  = (const float*)d_in[5];
    const float* flag_emb  = (const float*)d_in[6];
    const float* t1_w      = (const float*)d_in[7];
    const float* t1_b      = (const float*)d_in[8];
    const float* w1        = (const float*)d_in[9];
    const float* b1        = (const float*)d_in[10];
    const float* t2_w      = (const float*)d_in[11];
    const float* t2_b      = (const float*)d_in[12];
    const float* w2        = (const float*)d_in[13];
    const float* b2        = (const float*)d_in[14];

    float* h  = (float*)d_ws;                        // 4 MB (reused for h2)
    float* tt = h  + (size_t)NROWS*DD;               // 4 MB sigmoid(out1)
    unsigned short* hT  = (unsigned short*)(tt + (size_t)NROWS*DD); // 4 MB region
    unsigned short* Wb1 = hT  + (size_t)NROWS*DD;    // 128 KB bf16
    unsigned short* Wb2 = Wb1 + (size_t)DD*DD;       // 128 KB bf16
    float* a1 = (float*)(Wb2 + (size_t)DD*DD);
    float* c1 = a1 + NROWS;
    float* a2 = c1 + NROWS;
    float* c2 = a2 + NROWS;

    conv_w<<<DD*DD/256, 256, 0, stream>>>(t1_w, t2_w, Wb1, Wb2);
    lin_mfma<<<NROWS/16, 256, 0, stream>>>(Wb1, t1_b, node_emb, head_nodes, h, hT);
    row_scalars<<<NROWS/4, 256, 0, stream>>>(h, head_flag, flag_emb, w1, a1, c1);
    attn_fused<<<BB*(NN/JT), 256, 0, stream>>>(adj, etype, edge_emb, w1, b1,
                                               a1, c1, hT, tt, 1);
    lin_mfma<<<NROWS/16, 256, 0, stream>>>(Wb2, t2_b, tt, nullptr, h, hT);
    row_scalars<<<NROWS/4, 256, 0, stream>>>(h, head_flag, flag_emb, w2, a2, c2);
    attn_fused<<<BB*(NN/JT), 256, 0, stream>>>(adj, etype, edge_emb, w2, b2,
                                               a2, c2, hT, (float*)d_out, 0);
}

// Round 5
// 61.369 us; speedup vs baseline: 2.5808x; 1.2916x over previous
//
#include <hip/hip_runtime.h>
#include <hip/hip_bf16.h>

#define BB 8
#define NN 512
#define DD 256
#define NROWS (BB*NN)   // 4096
#define JT 16           // attn j-tile

using bf16x8 = __attribute__((ext_vector_type(8))) short;
using f32x4  = __attribute__((ext_vector_type(4))) float;
typedef unsigned short us_t;

__device__ __forceinline__ us_t f2bf(float x) {
    union { float f; unsigned int u; } v; v.f = x;
    unsigned int r = (v.u + 0x7fffu + ((v.u >> 16) & 1u)) >> 16;
    return (us_t)r;
}

// Weights f32->bf16 (blocks 0..255) + pack adj/etype into 1 byte (blocks 256..2303)
__global__ __launch_bounds__(256) void prep(
    const float* __restrict__ w1f, const float* __restrict__ w2f,
    us_t* __restrict__ o1, us_t* __restrict__ o2,
    const int* __restrict__ adj, const int* __restrict__ et,
    unsigned char* __restrict__ pk)
{
    const int t = threadIdx.x, blk = blockIdx.x;
    if (blk < 256) {
        int i = blk*256 + t;
        o1[i] = f2bf(w1f[i]);
        o2[i] = f2bf(w2f[i]);
    } else {
        int g = ((blk-256)*256 + t)*4;
        int4 av = *(const int4*)(adj+g);
        int4 ev = *(const int4*)(et+g);
        uchar4 u;
        u.x = (unsigned char)((ev.x&15)|(av.x<<4));
        u.y = (unsigned char)((ev.y&15)|(av.y<<4));
        u.z = (unsigned char)((ev.z&15)|(av.z<<4));
        u.w = (unsigned char)((ev.w&15)|(av.w<<4));
        *(uchar4*)(pk+g) = u;
    }
}

// MFMA linear + fused a/c scalars.
// Block: 16 rows x 256 d, 4 waves. Writes hT[b][d][i] bf16, a[row], c[row].
// Input: Xf (f32, optionally gathered via idx) or Xb (bf16 row-major).
__global__ __launch_bounds__(256) void lin_mfma(
    const us_t* __restrict__ Wbf, const float* __restrict__ bias,
    const float* __restrict__ Xf, const us_t* __restrict__ Xb,
    const int* __restrict__ idx,
    const float* __restrict__ wvec, const int* __restrict__ flagidx,
    const float* __restrict__ flag_emb,
    us_t* __restrict__ hT, float* __restrict__ aout, float* __restrict__ cout)
{
    __shared__ float redA[64], redC[64];
    const int t = threadIdx.x;
    const int wave = t >> 6, lane = t & 63;
    const int lrow = lane & 15, kg = lane >> 4;
    const int r0 = blockIdx.x * 16;
    const int dw = wave * 64;

    const int arow = r0 + lrow;
    const int nid = idx ? idx[arow] : arow;

    f32x4 acc[4];
    #pragma unroll
    for (int n = 0; n < 4; ++n) acc[n] = (f32x4){0.f, 0.f, 0.f, 0.f};

    if (Xb) {
        const us_t* xr = Xb + (size_t)nid * DD;
        #pragma unroll
        for (int ks = 0; ks < DD/32; ++ks) {
            bf16x8 af = *(const bf16x8*)(xr + ks*32 + kg*8);
            #pragma unroll
            for (int n = 0; n < 4; ++n) {
                bf16x8 bf = *(const bf16x8*)(Wbf + (size_t)(dw + n*16 + lrow)*DD
                                              + ks*32 + kg*8);
                acc[n] = __builtin_amdgcn_mfma_f32_16x16x32_bf16(af, bf, acc[n], 0, 0, 0);
            }
        }
    } else {
        const float4* xr = (const float4*)(Xf + (size_t)nid * DD);
        #pragma unroll
        for (int ks = 0; ks < DD/32; ++ks) {
            float4 xa = xr[ks*8 + kg*2];
            float4 xb = xr[ks*8 + kg*2 + 1];
            bf16x8 af;
            af[0] = (short)f2bf(xa.x); af[1] = (short)f2bf(xa.y);
            af[2] = (short)f2bf(xa.z); af[3] = (short)f2bf(xa.w);
            af[4] = (short)f2bf(xb.x); af[5] = (short)f2bf(xb.y);
            af[6] = (short)f2bf(xb.z); af[7] = (short)f2bf(xb.w);
            #pragma unroll
            for (int n = 0; n < 4; ++n) {
                bf16x8 bf = *(const bf16x8*)(Wbf + (size_t)(dw + n*16 + lrow)*DD
                                              + ks*32 + kg*8);
                acc[n] = __builtin_amdgcn_mfma_f32_16x16x32_bf16(af, bf, acc[n], 0, 0, 0);
            }
        }
    }

    // epilogue: D row (m) = kg*4+r, D col (d) = dw + n*16 + lrow
    const int b  = r0 >> 9;
    const int i0 = (r0 & 511) + kg*4;
    float pa[4] = {0.f,0.f,0.f,0.f}, pc[4] = {0.f,0.f,0.f,0.f};
    #pragma unroll
    for (int n = 0; n < 4; ++n) {
        int d = dw + n*16 + lrow;
        float bv = bias[d];
        float whd = wvec[d], wtd = wvec[256+d];
        ushort4 u;
        #pragma unroll
        for (int r = 0; r < 4; ++r) {
            float v = acc[n][r] + bv;
            ((us_t*)&u)[r] = f2bf(v);
            pa[r] += v * whd;
            pc[r] += v * wtd;
        }
        *(ushort4*)&hT[(size_t)b*DD*NN + (size_t)d*NN + i0] = u;
    }
    // reduce pa/pc over the 16 lanes sharing kg
    #pragma unroll
    for (int r = 0; r < 4; ++r) {
        #pragma unroll
        for (int m = 1; m < 16; m <<= 1) {
            pa[r] += __shfl_xor(pa[r], m);
            pc[r] += __shfl_xor(pc[r], m);
        }
    }
    if (lrow == 0) {
        #pragma unroll
        for (int r = 0; r < 4; ++r) {
            redA[wave*16 + kg*4 + r] = pa[r];
            redC[wave*16 + kg*4 + r] = pc[r];
        }
    }
    __syncthreads();
    if (t < 128) {
        const int m = t >> 3, sub = t & 7;
        const int fi = flagidx[r0 + m];
        float fa = 0.f, fc = 0.f;
        #pragma unroll
        for (int q = 0; q < 4; ++q) {
            int e = sub*4 + q;
            float fe = flag_emb[fi*32 + e];
            fa += fe * wvec[512 + e];
            fc += fe * wvec[544 + e];
        }
        #pragma unroll
        for (int mm = 1; mm < 8; mm <<= 1) {
            fa += __shfl_xor(fa, mm);
            fc += __shfl_xor(fc, mm);
        }
        if (sub == 0) {
            float sa = fa, sc = fc;
            #pragma unroll
            for (int wv = 0; wv < 4; ++wv) { sa += redA[wv*16 + m]; sc += redC[wv*16 + m]; }
            aout[r0 + m] = sa;
            cout[r0 + m] = sc;
        }
    }
}

// One block per (b, 16-column tile). logits from packed bytes -> softmax over i
// -> bf16 P in LDS -> MFMA out[j,d] = sum_i P[i,j] h[i,d] via hT[b][d][i].
__global__ __launch_bounds__(256) void attn_fused(
    const unsigned char* __restrict__ pk,
    const float* __restrict__ edge_emb, const float* __restrict__ w,
    const float* __restrict__ bptr,
    const float* __restrict__ a, const float* __restrict__ c,
    const us_t* __restrict__ hT,
    float* __restrict__ outf, us_t* __restrict__ outb)
{
    __shared__ __align__(16) float p[NN][JT+1];           // 34.8 KB
    __shared__ __align__(16) us_t Pb[JT][NN+8];           // 16.6 KB
    __shared__ float as[NN];                              // 2 KB
    __shared__ float edot[16];
    __shared__ float cjs[JT];
    __shared__ float red[16][JT];
    __shared__ float mj[JT];
    __shared__ float invden[JT];

    const int t = threadIdx.x;
    const int b  = blockIdx.x >> 5;
    const int j0 = (blockIdx.x & 31) * JT;

    as[t]       = a[b*NN + t];
    as[256 + t] = a[b*NN + 256 + t];
    if (t < 16) {
        float s = 0.f;
        for (int e2 = 0; e2 < 32; ++e2)
            s += edge_emb[t*32 + e2] * w[576 + e2];
        edot[t] = s;
    } else if (t < 32) {
        cjs[t-16] = c[b*NN + j0 + (t-16)];
    }
    const float bias = bptr[0];
    __syncthreads();

    // ---- logits from packed bytes (4 edges per load) ----
    const unsigned char* pkb = pk + (size_t)b*NN*NN + j0;
    #pragma unroll
    for (int it = 0; it < NN*JT/1024; ++it) {
        int lid4 = (it*256 + t) * 4;     // element index within [512][16] tile
        int i = lid4 >> 4, jj = lid4 & 15;
        uchar4 u = *(const uchar4*)(pkb + (size_t)i*NN + jj);
        float base = as[i] + bias;
        unsigned char uv[4] = {u.x, u.y, u.z, u.w};
        #pragma unroll
        for (int q = 0; q < 4; ++q) {
            float l = base + cjs[jj+q] + edot[uv[q] & 15];
            l = (l > 0.f) ? l : 0.1f*l;
            p[i][jj+q] = (uv[q] >> 4) ? l : -1.0e30f;
        }
    }
    __syncthreads();

    // ---- softmax over i (per column j) ----
    const int j = t & 15, grp = t >> 4;   // grp 0..15, each handles 32 i's
    float m = -3.0e38f;
    #pragma unroll
    for (int s = 0; s < 32; ++s) m = fmaxf(m, p[grp + s*16][j]);
    red[grp][j] = m;
    __syncthreads();
    if (t < 16) {
        float mm = red[0][t];
        for (int g2 = 1; g2 < 16; ++g2) mm = fmaxf(mm, red[g2][t]);
        mj[t] = mm;
    }
    __syncthreads();
    const float mmax = mj[j];
    float ssum = 0.f;
    #pragma unroll
    for (int s = 0; s < 32; ++s) {
        float v = __expf(p[grp + s*16][j] - mmax);
        p[grp + s*16][j] = v;
        ssum += v;
    }
    red[grp][j] = ssum;
    __syncthreads();
    if (t < 16) {
        float sm = 0.f;
        for (int g2 = 0; g2 < 16; ++g2) sm += red[g2][t];
        invden[t] = 1.f / sm;
    }
    __syncthreads();

    // ---- normalize + pack transposed bf16: Pb[j][i] ----
    const float inv = invden[j];
    #pragma unroll
    for (int s = 0; s < 16; ++s) {
        int i = grp*2 + s*32;
        ushort2 u;
        u.x = f2bf(p[i  ][j] * inv);
        u.y = f2bf(p[i+1][j] * inv);
        *(ushort2*)&Pb[j][i] = u;
    }
    __syncthreads();

    // ---- MFMA: out[16 j][256 d] = P^T (16x512) x h (512x256) ----
    const int wave = t >> 6, lane = t & 63;
    const int dw = wave * 64;
    const int lrow = lane & 15;          // A row (j) / B col (d)
    const int kg   = lane >> 4;          // k-group
    f32x4 acc[4];
    #pragma unroll
    for (int n = 0; n < 4; ++n) acc[n] = (f32x4){0.f,0.f,0.f,0.f};

    const us_t* hTb = hT + (size_t)b*DD*NN;
    const us_t* hp[4];
    #pragma unroll
    for (int n = 0; n < 4; ++n)
        hp[n] = hTb + (size_t)(dw + n*16 + lrow)*NN + kg*8;

    #pragma unroll 2
    for (int ks = 0; ks < NN/32; ++ks) {
        int k0 = ks*32;
        bf16x8 afr = *(const bf16x8*)&Pb[lrow][kg*8 + k0];
        #pragma unroll
        for (int n = 0; n < 4; ++n) {
            bf16x8 bfr = *(const bf16x8*)(hp[n] + k0);
            acc[n] = __builtin_amdgcn_mfma_f32_16x16x32_bf16(afr, bfr, acc[n], 0, 0, 0);
        }
    }

    // ---- epilogue: C/D col=lane&15 (d), row=(lane>>4)*4+reg (j) ----
    #pragma unroll
    for (int n = 0; n < 4; ++n) {
        #pragma unroll
        for (int r = 0; r < 4; ++r) {
            float v = acc[n][r];
            int jj = j0 + kg*4 + r;
            int dd = dw + n*16 + lrow;
            size_t o = (size_t)(b*NN + jj)*DD + dd;
            if (outb) outb[o] = f2bf(1.f/(1.f + __expf(-v)));
            else      outf[o] = v;
        }
    }
}

extern "C" void kernel_launch(void* const* d_in, const int* in_sizes, int n_in,
                              void* d_out, int out_size, void* d_ws, size_t ws_size,
                              hipStream_t stream) {
    (void)in_sizes; (void)n_in; (void)out_size; (void)ws_size;
    const int*   adj       = (const int*)d_in[0];
    const int*   head_nodes= (const int*)d_in[1];
    const int*   head_flag = (const int*)d_in[2];
    const int*   etype     = (const int*)d_in[3];
    const float* node_emb  = (const float*)d_in[4];
    const float* edge_emb  = (const float*)d_in[5];
    const float* flag_emb  = (const float*)d_in[6];
    const float* t1_w      = (const float*)d_in[7];
    const float* t1_b      = (const float*)d_in[8];
    const float* w1        = (const float*)d_in[9];
    const float* b1        = (const float*)d_in[10];
    const float* t2_w      = (const float*)d_in[11];
    const float* t2_b      = (const float*)d_in[12];
    const float* w2        = (const float*)d_in[13];
    const float* b2        = (const float*)d_in[14];

    us_t* hT  = (us_t*)d_ws;                         // 2 MB bf16 [b][d][i]
    us_t* tt  = hT  + (size_t)NROWS*DD;              // 2 MB bf16 sigmoid(out1)
    us_t* Wb1 = tt  + (size_t)NROWS*DD;              // 128 KB
    us_t* Wb2 = Wb1 + (size_t)DD*DD;                 // 128 KB
    unsigned char* pk = (unsigned char*)(Wb2 + (size_t)DD*DD);  // 2 MB
    float* a1 = (float*)(pk + (size_t)BB*NN*NN);
    float* c1 = a1 + NROWS;
    float* a2 = c1 + NROWS;
    float* c2 = a2 + NROWS;

    prep<<<256 + BB*NN*NN/1024, 256, 0, stream>>>(t1_w, t2_w, Wb1, Wb2,
                                                  adj, etype, pk);
    lin_mfma<<<NROWS/16, 256, 0, stream>>>(Wb1, t1_b, node_emb, nullptr, head_nodes,
                                           w1, head_flag, flag_emb, hT, a1, c1);
    attn_fused<<<BB*(NN/JT), 256, 0, stream>>>(pk, edge_emb, w1, b1, a1, c1, hT,
                                               nullptr, tt);
    lin_mfma<<<NROWS/16, 256, 0, stream>>>(Wb2, t2_b, nullptr, tt, nullptr,
                                           w2, head_flag, flag_emb, hT, a2, c2);
    attn_fused<<<BB*(NN/JT), 256, 0, stream>>>(pk, edge_emb, w2, b2, a2, c2, hT,
                                               (float*)d_out, nullptr);
}